// Round 11
// baseline (160.105 us; speedup 1.0000x reference)
//
#include <hip/hip_runtime.h>
#include <hip/hip_fp16.h>

#define DIMN 64
#define NNB 16
#define NREL 33
#define WPB 4          // batch elements (waves) per block, 1 elem per wave
#define XSTR 68        // LDS tile row stride in floats (68%32=4 -> 2-way banks = free)
#define WFRAG_BYTES 16384   // w0 hi/lo fragments region at start of d_ws
#define ATTN_EPS 0.001953125f   // 2^-9: skip hop-2 rows with negligible softmax weight

typedef float        floatx4 __attribute__((ext_vector_type(4)));
typedef short        shortx8 __attribute__((ext_vector_type(8)));
typedef unsigned int uintx2  __attribute__((ext_vector_type(2)));

__device__ __forceinline__ float bcastf(float x, int lane) {
    return __int_as_float(__builtin_amdgcn_readlane(__float_as_int(x), lane));
}

// ---- prep: split W0 into bf16 hi/lo MFMA B-fragments (16 KB). No entity
// table work: fp16 conversion (r4) and L3 warm sweep (r6) both measured as
// net-neutral-or-worse; kgs gather behavior is insensitive to priming.
__global__ void prep_kernel(const float* __restrict__ W0, unsigned short* __restrict__ wsp)
{
    const int tid = blockIdx.x * blockDim.x + threadIdx.x;
    if (tid < 512) {
        const int l = tid & 63;
        const int t = (tid >> 6) & 3;
        const int ks = tid >> 8;
        const int k0 = ks * 32 + (l >> 4) * 8;
        const int n  = t * 16 + (l & 15);
        const unsigned base = ((unsigned)(ks * 4 + t) * 64 + l) * 8;
        #pragma unroll
        for (int j = 0; j < 8; ++j) {
            const float x = W0[(k0 + j) * DIMN + n];
            const unsigned u  = __float_as_uint(x);
            const unsigned uh = u & 0xFFFF0000u;
            const float lf = x - __uint_as_float(uh);       // exact residual
            wsp[base + j]        = (unsigned short)(u >> 16);
            wsp[4096 + base + j] = (unsigned short)(__float_as_uint(lf) >> 16);
        }
    }
}

// Round-16: r9's 4-deep pipeline + FORCED 128-VGPR allocation via a physical
// register clobber (asm "" ::: "v127"). Evidence trail: 4-deep raises the
// random-line service rate (kgs 57->49 us rocprof) but the allocator insists
// on the 64-reg tier and spills ~22 MB of scratch, which regresses the graded
// bench (149.4->160). The spill buys occupancy that CANNOT exist: LDS
// (36.9 KB/block) and the 4096-wave grid both cap at 16 waves/CU, which the
// 128-reg tier also supports. waves_per_eu(4,4) was ignored (r10, null);
// clobbering v127 forces allocation >=128 so the ~111-reg live set fits
// spill-free. Single variable vs r9.
__global__ __launch_bounds__(64 * WPB, 4)
void kgs_kernel(const int* __restrict__ u, const int* __restrict__ v,
                const int* __restrict__ adj, const int* __restrict__ rel_adj,
                const float* __restrict__ usr_emb, const float* __restrict__ ent_emb,
                const float* __restrict__ rel_emb,
                const float* __restrict__ W0, const float* __restrict__ b0,
                const float* __restrict__ W1, const float* __restrict__ b1,
                const unsigned short* __restrict__ wsp,
                float* __restrict__ out, int B)
{
    const int tid  = threadIdx.x;
    const int wid  = tid >> 6;
    const int d    = tid & 63;
    const int n16  = d & 15;
    const int quad = d >> 4;
    int b = blockIdx.x * WPB + wid;
    if (b >= B) b = B - 1;

    // all LDS wave-private -> no __syncthreads anywhere
    __shared__ __align__(16) float user_sh[WPB][DIMN];
    __shared__ float ur_sh[WPB][NREL + 3];
    __shared__ __align__(16) float sv_sh[WPB][NNB * XSTR];  // hop-1 sv rows
    __shared__ __align__(16) float gbuf[WPB][NNB * XSTR];   // agg rows, then h1

    const int uu = u[b];
    const int vv = v[b];

    const float user_d = usr_emb[(size_t)uu * DIMN + d];
    const int e1n = adj[vv * NNB + n16];
    const int r1n = rel_adj[vv * NNB + n16];
    const float sv0 = ent_emb[(size_t)vv * DIMN + d];
    user_sh[wid][d] = user_d;

    // ---- sv tile: 4 loads cover all 16 hop-1 rows (split layout)
    floatx4 svv[4];
    #pragma unroll
    for (int q = 0; q < 4; ++q) {
        const int em = __shfl(e1n, 4 * q + quad);           // row id for this lane
        svv[q] = *(const floatx4*)(ent_emb + (size_t)em * DIMN + 4 * n16);
    }

    // ---- index prefetch for hop-2
    int e2n_r[NNB], r2n_r[NNB];
    #pragma unroll
    for (int m = 0; m < NNB; ++m) {
        const int em = __builtin_amdgcn_readlane(e1n, m);
        e2n_r[m] = adj[em * NNB + n16];
        r2n_r[m] = rel_adj[em * NNB + n16];
    }

    // ---- ur table: 33 user-rel dots (wave-private, same-wave LDS)
    if (d < NREL) {
        const float* re = rel_emb + d * DIMN;
        float acc = 0.f;
        #pragma unroll
        for (int k = 0; k < DIMN; k += 4) {
            const float4 uk = *(const float4*)(&user_sh[wid][k]);
            const float4 rk = *(const float4*)(re + k);
            acc = fmaf(uk.x, rk.x, acc);
            acc = fmaf(uk.y, rk.y, acc);
            acc = fmaf(uk.z, rk.z, acc);
            acc = fmaf(uk.w, rk.w, acc);
        }
        ur_sh[wid][d] = acc;
    }

    // park sv tile in LDS (b128 writes, 4 rows per instr)
    #pragma unroll
    for (int q = 0; q < 4; ++q)
        *(floatx4*)(&sv_sh[wid][(4 * q + quad) * XSTR + 4 * n16]) = svv[q];

    // ---- softmax attention for all 16 hop-1 groups (lane layout n16)
    float attn[NNB];
    #pragma unroll
    for (int m = 0; m < NNB; ++m) {
        const float e = __expf(ur_sh[wid][r2n_r[m]]);
        float s = e;
        s += __shfl_xor(s, 1);
        s += __shfl_xor(s, 2);
        s += __shfl_xor(s, 4);
        s += __shfl_xor(s, 8);
        attn[m] = e * __builtin_amdgcn_rcpf(s);
    }

    // ---- hop-2 gather+aggregate, 4-deep pipeline + branchless threshold skip
    floatx4 gA[4], gB[4], gC[4], gD[4];

    auto ISSUE = [&](int m, floatx4* g) {
        #pragma unroll
        for (int q = 0; q < 4; ++q) {
            const int src = 4 * q + quad;
            const int en  = __shfl(e2n_r[m], src);          // row id (VGPR)
            const float w = __shfl(attn[m], src);           // weight for that row
            const int ens = (w >= ATTN_EPS) ? en : 0;       // dummy hot row 0
            g[q] = *(const floatx4*)(ent_emb + (size_t)ens * DIMN + 4 * n16);
        }
    };
    auto REDUCE = [&](int m, floatx4* g) {
        floatx4 acc4 = (floatx4){0.f, 0.f, 0.f, 0.f};
        #pragma unroll
        for (int q = 0; q < 4; ++q) {
            const int src = 4 * q + quad;
            const float w = __shfl(attn[m], src);           // recompute (saves regs)
            const float aw = (w >= ATTN_EPS) ? w : 0.f;     // exact skip semantics
            acc4[0] = fmaf(aw, g[q][0], acc4[0]);
            acc4[1] = fmaf(aw, g[q][1], acc4[1]);
            acc4[2] = fmaf(aw, g[q][2], acc4[2]);
            acc4[3] = fmaf(aw, g[q][3], acc4[3]);
        }
        #pragma unroll
        for (int c = 0; c < 4; ++c) {                       // reduce over quads
            acc4[c] += __shfl_xor(acc4[c], 16);
            acc4[c] += __shfl_xor(acc4[c], 32);
        }
        if (d < 16)
            *(floatx4*)(&gbuf[wid][m * XSTR + 4 * d]) = acc4;
    };

    // prologue: 4 groups (16 dwordx4) in flight
    ISSUE(0, gA); ISSUE(1, gB); ISSUE(2, gC); ISSUE(3, gD);
    // steady state: retire a group, refill the same buffer (indices static)
    #pragma unroll
    for (int mb = 0; mb < 3; ++mb) {
        REDUCE(4 * mb + 0, gA); ISSUE(4 * mb + 4, gA);
        REDUCE(4 * mb + 1, gB); ISSUE(4 * mb + 5, gB);
        REDUCE(4 * mb + 2, gC); ISSUE(4 * mb + 6, gC);
        REDUCE(4 * mb + 3, gD); ISSUE(4 * mb + 7, gD);
    }
    // epilogue
    REDUCE(12, gA); REDUCE(13, gB); REDUCE(14, gC); REDUCE(15, gD);

    // ---- A-fragments: xs = sv + agg; bf16 hi/lo split
    shortx8 Ahi[2], Alo[2];
    #pragma unroll
    for (int ks = 0; ks < 2; ++ks) {
        const int off = (d & 15) * XSTR + quad * 8 + ks * 32;
        const floatx4 sa = *(const floatx4*)(&sv_sh[wid][off]);
        const floatx4 sb = *(const floatx4*)(&sv_sh[wid][off + 4]);
        const floatx4 ga = *(const floatx4*)(&gbuf[wid][off]);
        const floatx4 gb = *(const floatx4*)(&gbuf[wid][off + 4]);
        unsigned uh[8], ul[8];
        #pragma unroll
        for (int j = 0; j < 8; ++j) {
            const float x = (j < 4) ? (sa[j] + ga[j]) : (sb[j - 4] + gb[j - 4]);
            const unsigned ub = __float_as_uint(x);
            uh[j] = ub & 0xFFFF0000u;
            ul[j] = __float_as_uint(x - __uint_as_float(uh[j]));
        }
        union { int i[4]; shortx8 s; } ch, cl;
        #pragma unroll
        for (int p = 0; p < 4; ++p) {
            ch.i[p] = (int)(uh[2 * p + 1] | (uh[2 * p] >> 16));
            cl.i[p] = (int)((ul[2 * p + 1] & 0xFFFF0000u) | (ul[2 * p] >> 16));
        }
        Ahi[ks] = ch.s;
        Alo[ks] = cl.s;
    }

    // ---- MFMA: O = Xhi*Whi + Xhi*Wlo + Xlo*Whi (fp32-accurate 3-term)
    const shortx8* wf = (const shortx8*)wsp;
    floatx4 acc[4];
    #pragma unroll
    for (int t = 0; t < 4; ++t) acc[t] = (floatx4){0.f, 0.f, 0.f, 0.f};
    #pragma unroll
    for (int t = 0; t < 4; ++t) {
        #pragma unroll
        for (int ks = 0; ks < 2; ++ks) {
            const int f = ks * 4 + t;
            const shortx8 bhi = wf[f * 64 + d];
            const shortx8 blo = wf[512 + f * 64 + d];
            acc[t] = __builtin_amdgcn_mfma_f32_16x16x32_bf16(Ahi[ks], bhi, acc[t], 0, 0, 0);
            acc[t] = __builtin_amdgcn_mfma_f32_16x16x32_bf16(Ahi[ks], blo, acc[t], 0, 0, 0);
            acc[t] = __builtin_amdgcn_mfma_f32_16x16x32_bf16(Alo[ks], bhi, acc[t], 0, 0, 0);
        }
    }

    // ---- bias + sigmoid in D-layout (row=quad*4+reg, col=t*16+n16) -> gbuf (reuse)
    #pragma unroll
    for (int t = 0; t < 4; ++t) {
        const float bv = b0[t * 16 + n16];
        #pragma unroll
        for (int reg = 0; reg < 4; ++reg) {
            const float o = acc[t][reg] + bv;
            const int m = quad * 4 + reg;
            gbuf[wid][m * XSTR + t * 16 + n16] = 1.f / (1.f + __expf(-o));
        }
    }

    // ================= hop-0 (per wave, own elem) =============================
    const float e0 = __expf(ur_sh[wid][r1n]);
    float sum0 = e0;
    sum0 += __shfl_xor(sum0, 1);
    sum0 += __shfl_xor(sum0, 2);
    sum0 += __shfl_xor(sum0, 4);
    sum0 += __shfl_xor(sum0, 8);
    const float attn0 = e0 * __builtin_amdgcn_rcpf(sum0);

    float agg0 = 0.f, agg1 = 0.f;
    #pragma unroll
    for (int n = 0; n < NNB; ++n) {
        const float an = bcastf(attn0, n);
        agg0 = fmaf(an, sv_sh[wid][n * XSTR + d], agg0);
        agg1 = fmaf(an, gbuf[wid][n * XSTR + d], agg1);
    }

    // ---- iter0/hop0: sigmoid((sv0+agg0) @ W0 + b0)
    const float x0 = sv0 + agg0;
    float a0 = 0.f, a1 = 0.f, a2 = 0.f, a3 = 0.f;
    for (int k = 0; k < DIMN; k += 4) {
        const float* wr = W0 + k * DIMN;
        a0 = fmaf(bcastf(x0, k + 0), wr[d], a0);
        a1 = fmaf(bcastf(x0, k + 1), wr[DIMN + d], a1);
        a2 = fmaf(bcastf(x0, k + 2), wr[2 * DIMN + d], a2);
        a3 = fmaf(bcastf(x0, k + 3), wr[3 * DIMN + d], a3);
    }
    const float o0 = b0[d] + ((a0 + a1) + (a2 + a3));
    const float h0 = 1.f / (1.f + __expf(-o0));

    // ---- iter1/hop0: tanh((h0+agg1) @ W1 + b1)
    const float x1 = h0 + agg1;
    float c0 = 0.f, c1 = 0.f, c2 = 0.f, c3 = 0.f;
    for (int k = 0; k < DIMN; k += 4) {
        const float* wr = W1 + k * DIMN;
        c0 = fmaf(bcastf(x1, k + 0), wr[d], c0);
        c1 = fmaf(bcastf(x1, k + 1), wr[DIMN + d], c1);
        c2 = fmaf(bcastf(x1, k + 2), wr[2 * DIMN + d], c2);
        c3 = fmaf(bcastf(x1, k + 3), wr[3 * DIMN + d], c3);
    }
    const float o1 = b1[d] + ((c0 + c1) + (c2 + c3));
    const float item_d = 1.f - 2.f / (1.f + __expf(2.f * o1));  // tanh

    // ---- final: sigmoid(user . item)
    float p = user_d * item_d;
    p += __shfl_xor(p, 1);
    p += __shfl_xor(p, 2);
    p += __shfl_xor(p, 4);
    p += __shfl_xor(p, 8);
    p += __shfl_xor(p, 16);
    p += __shfl_xor(p, 32);
    if (d == 0) out[b] = 1.f / (1.f + __expf(-p));

    // Force the register allocator onto the 128-VGPR tier: v127 is marked
    // clobbered, so allocation must cover it. LDS (4 blocks/CU) and the grid
    // (4096 waves) cap occupancy at 16 waves/CU either way -- spilling to
    // stay at 64 VGPR (r9/r10: 22 MB scratch) buys nothing. No code emitted.
    asm volatile("" ::: "v127");
}

extern "C" void kernel_launch(void* const* d_in, const int* in_sizes, int n_in,
                              void* d_out, int out_size, void* d_ws, size_t ws_size,
                              hipStream_t stream) {
    const int*   u       = (const int*)d_in[0];
    const int*   v       = (const int*)d_in[1];
    const int*   adj     = (const int*)d_in[2];
    const int*   rel_adj = (const int*)d_in[3];
    const float* usr_emb = (const float*)d_in[4];
    const float* ent_emb = (const float*)d_in[5];
    const float* rel_emb = (const float*)d_in[6];
    const float* W0      = (const float*)d_in[7];
    const float* b0      = (const float*)d_in[8];
    const float* W1      = (const float*)d_in[9];
    const float* b1      = (const float*)d_in[10];
    float* out = (float*)d_out;
    unsigned short* wsp = (unsigned short*)d_ws;

    const int B = in_sizes[0];                 // 4096

    prep_kernel<<<dim3(2), dim3(256), 0, stream>>>(W0, wsp);

    const int grid = (B + WPB - 1) / WPB;
    kgs_kernel<<<dim3(grid), dim3(64 * WPB), 0, stream>>>(
        u, v, adj, rel_adj, usr_emb, ent_emb, rel_emb, W0, b0, W1, b1,
        wsp, out, B);
}

// Round 12
// 145.487 us; speedup vs baseline: 1.1005x; 1.1005x over previous
//
#include <hip/hip_runtime.h>
#include <hip/hip_fp16.h>

#define DIMN 64
#define NNB 16
#define NREL 33
#define WPB 4          // batch elements (waves) per block, 1 elem per wave
#define XSTR 68        // LDS tile row stride in floats (68%32=4 -> 2-way banks = free)
#define ATTN_EPS 0.001953125f   // 2^-9: skip hop-2 rows with negligible softmax weight

typedef float        floatx4 __attribute__((ext_vector_type(4)));
typedef short        shortx8 __attribute__((ext_vector_type(8)));
typedef unsigned int uintx2  __attribute__((ext_vector_type(2)));

__device__ __forceinline__ float bcastf(float x, int lane) {
    return __int_as_float(__builtin_amdgcn_readlane(__float_as_int(x), lane));
}

// Round-17: revert to the r5 champion (149.4 us; 2-deep pipeline, fp32
// gathers, branchless skip) + fold the W0 bf16 hi/lo fragment split INTO kgs
// (prep kernel deleted, zero workspace use, single dispatch).
// Closed axes (measured): occupancy (grid+LDS lock 16 waves/CU; forced-tier
// splits spill, r1), line count (3x fewer lines = 0 delta, r3/r4), priming
// (L3 sweep null, r6), 4-deep MLP (steady 57->49 but 22 MB spill regresses
// the graded pass; allocator unforceable via heuristic/attr/clobber, r9-r11).
__global__ __launch_bounds__(64 * WPB, 4)
void kgs_kernel(const int* __restrict__ u, const int* __restrict__ v,
                const int* __restrict__ adj, const int* __restrict__ rel_adj,
                const float* __restrict__ usr_emb, const float* __restrict__ ent_emb,
                const float* __restrict__ rel_emb,
                const float* __restrict__ W0, const float* __restrict__ b0,
                const float* __restrict__ W1, const float* __restrict__ b1,
                float* __restrict__ out, int B)
{
    const int tid  = threadIdx.x;
    const int wid  = tid >> 6;
    const int d    = tid & 63;
    const int n16  = d & 15;
    const int quad = d >> 4;
    int b = blockIdx.x * WPB + wid;
    if (b >= B) b = B - 1;

    // all LDS wave-private -> no __syncthreads anywhere
    __shared__ __align__(16) float user_sh[WPB][DIMN];
    __shared__ float ur_sh[WPB][NREL + 3];
    __shared__ __align__(16) float sv_sh[WPB][NNB * XSTR];  // hop-1 sv rows
    __shared__ __align__(16) float gbuf[WPB][NNB * XSTR];   // agg rows, then h1

    const int uu = u[b];
    const int vv = v[b];

    const float user_d = usr_emb[(size_t)uu * DIMN + d];
    const int e1n = adj[vv * NNB + n16];
    const int r1n = rel_adj[vv * NNB + n16];
    const float sv0 = ent_emb[(size_t)vv * DIMN + d];
    user_sh[wid][d] = user_d;

    // ---- sv tile: 4 loads cover all 16 hop-1 rows (split layout)
    floatx4 svv[4];
    #pragma unroll
    for (int q = 0; q < 4; ++q) {
        const int em = __shfl(e1n, 4 * q + quad);           // row id for this lane
        svv[q] = *(const floatx4*)(ent_emb + (size_t)em * DIMN + 4 * n16);
    }

    // ---- index prefetch for hop-2
    int e2n_r[NNB], r2n_r[NNB];
    #pragma unroll
    for (int m = 0; m < NNB; ++m) {
        const int em = __builtin_amdgcn_readlane(e1n, m);
        e2n_r[m] = adj[em * NNB + n16];
        r2n_r[m] = rel_adj[em * NNB + n16];
    }

    // ---- ur table: 33 user-rel dots (wave-private, same-wave LDS)
    if (d < NREL) {
        const float* re = rel_emb + d * DIMN;
        float acc = 0.f;
        #pragma unroll
        for (int k = 0; k < DIMN; k += 4) {
            const float4 uk = *(const float4*)(&user_sh[wid][k]);
            const float4 rk = *(const float4*)(re + k);
            acc = fmaf(uk.x, rk.x, acc);
            acc = fmaf(uk.y, rk.y, acc);
            acc = fmaf(uk.z, rk.z, acc);
            acc = fmaf(uk.w, rk.w, acc);
        }
        ur_sh[wid][d] = acc;
    }

    // park sv tile in LDS (b128 writes, 4 rows per instr)
    #pragma unroll
    for (int q = 0; q < 4; ++q)
        *(floatx4*)(&sv_sh[wid][(4 * q + quad) * XSTR + 4 * n16]) = svv[q];

    // ---- softmax attention for all 16 hop-1 groups (lane layout n16)
    float attn[NNB];
    #pragma unroll
    for (int m = 0; m < NNB; ++m) {
        const float e = __expf(ur_sh[wid][r2n_r[m]]);
        float s = e;
        s += __shfl_xor(s, 1);
        s += __shfl_xor(s, 2);
        s += __shfl_xor(s, 4);
        s += __shfl_xor(s, 8);
        attn[m] = e * __builtin_amdgcn_rcpf(s);
    }

    // ---- hop-2 gather+aggregate, 2-deep pipeline + branchless threshold skip
    floatx4 gA[4], gB[4];
    float awA[4], awB[4];

    auto ISSUE = [&](int m, floatx4* g, float* aw) {
        #pragma unroll
        for (int q = 0; q < 4; ++q) {
            const int src = 4 * q + quad;
            const int en  = __shfl(e2n_r[m], src);          // row id (VGPR)
            const float w = __shfl(attn[m], src);           // weight for that row
            const bool keep = (w >= ATTN_EPS);
            const int ens = keep ? en : 0;                  // dummy hot row 0
            aw[q] = keep ? w : 0.f;                         // exact skip semantics
            g[q] = *(const floatx4*)(ent_emb + (size_t)ens * DIMN + 4 * n16);
        }
    };
    auto REDUCE = [&](int m, floatx4* g, float* aw) {
        floatx4 acc4 = (floatx4){0.f, 0.f, 0.f, 0.f};
        #pragma unroll
        for (int q = 0; q < 4; ++q) {
            acc4[0] = fmaf(aw[q], g[q][0], acc4[0]);
            acc4[1] = fmaf(aw[q], g[q][1], acc4[1]);
            acc4[2] = fmaf(aw[q], g[q][2], acc4[2]);
            acc4[3] = fmaf(aw[q], g[q][3], acc4[3]);
        }
        #pragma unroll
        for (int c = 0; c < 4; ++c) {                       // reduce over quads
            acc4[c] += __shfl_xor(acc4[c], 16);
            acc4[c] += __shfl_xor(acc4[c], 32);
        }
        if (d < 16)
            *(floatx4*)(&gbuf[wid][m * XSTR + 4 * d]) = acc4;
    };

    ISSUE(0, gA, awA);
    #pragma unroll
    for (int m = 0; m < NNB; ++m) {
        if ((m & 1) == 0) {
            if (m + 1 < NNB) ISSUE(m + 1, gB, awB);
            REDUCE(m, gA, awA);
        } else {
            if (m + 1 < NNB) ISSUE(m + 1, gA, awA);
            REDUCE(m, gB, awB);
        }
    }

    // ---- A-fragments: xs = sv + agg; bf16 hi/lo split
    shortx8 Ahi[2], Alo[2];
    #pragma unroll
    for (int ks = 0; ks < 2; ++ks) {
        const int off = (d & 15) * XSTR + quad * 8 + ks * 32;
        const floatx4 sa = *(const floatx4*)(&sv_sh[wid][off]);
        const floatx4 sb = *(const floatx4*)(&sv_sh[wid][off + 4]);
        const floatx4 ga = *(const floatx4*)(&gbuf[wid][off]);
        const floatx4 gb = *(const floatx4*)(&gbuf[wid][off + 4]);
        unsigned uh[8], ul[8];
        #pragma unroll
        for (int j = 0; j < 8; ++j) {
            const float x = (j < 4) ? (sa[j] + ga[j]) : (sb[j - 4] + gb[j - 4]);
            const unsigned ub = __float_as_uint(x);
            uh[j] = ub & 0xFFFF0000u;
            ul[j] = __float_as_uint(x - __uint_as_float(uh[j]));
        }
        union { int i[4]; shortx8 s; } ch, cl;
        #pragma unroll
        for (int p = 0; p < 4; ++p) {
            ch.i[p] = (int)(uh[2 * p + 1] | (uh[2 * p] >> 16));
            cl.i[p] = (int)((ul[2 * p + 1] & 0xFFFF0000u) | (ul[2 * p] >> 16));
        }
        Ahi[ks] = ch.s;
        Alo[ks] = cl.s;
    }

    // ---- MFMA: O = Xhi*Whi + Xhi*Wlo + Xlo*Whi (fp32-accurate 3-term).
    // B-fragments built in-register from W0 (prep kernel eliminated): thread d
    // needs W0[(ks*32 + (d>>4)*8 + j)*64 + t*16 + (d&15)], j=0..7 -- 64 scalar
    // loads of an L2-hot 16 KB matrix, packed with the same hi/lo idiom as the
    // A-fragments (bit-identical operands to the old wsp path).
    const int frow = (d >> 4) * 8;
    const int fcol = d & 15;
    floatx4 acc[4];
    #pragma unroll
    for (int t = 0; t < 4; ++t) acc[t] = (floatx4){0.f, 0.f, 0.f, 0.f};
    #pragma unroll
    for (int t = 0; t < 4; ++t) {
        #pragma unroll
        for (int ks = 0; ks < 2; ++ks) {
            unsigned uh[8], ul[8];
            #pragma unroll
            for (int j = 0; j < 8; ++j) {
                const float x = W0[(ks * 32 + frow + j) * DIMN + t * 16 + fcol];
                const unsigned ub = __float_as_uint(x);
                uh[j] = ub & 0xFFFF0000u;
                ul[j] = __float_as_uint(x - __uint_as_float(uh[j]));
            }
            union { int i[4]; shortx8 s; } ch, cl;
            #pragma unroll
            for (int p = 0; p < 4; ++p) {
                ch.i[p] = (int)(uh[2 * p + 1] | (uh[2 * p] >> 16));
                cl.i[p] = (int)((ul[2 * p + 1] & 0xFFFF0000u) | (ul[2 * p] >> 16));
            }
            acc[t] = __builtin_amdgcn_mfma_f32_16x16x32_bf16(Ahi[ks], ch.s, acc[t], 0, 0, 0);
            acc[t] = __builtin_amdgcn_mfma_f32_16x16x32_bf16(Ahi[ks], cl.s, acc[t], 0, 0, 0);
            acc[t] = __builtin_amdgcn_mfma_f32_16x16x32_bf16(Alo[ks], ch.s, acc[t], 0, 0, 0);
        }
    }

    // ---- bias + sigmoid in D-layout (row=quad*4+reg, col=t*16+n16) -> gbuf (reuse)
    #pragma unroll
    for (int t = 0; t < 4; ++t) {
        const float bv = b0[t * 16 + n16];
        #pragma unroll
        for (int reg = 0; reg < 4; ++reg) {
            const float o = acc[t][reg] + bv;
            const int m = quad * 4 + reg;
            gbuf[wid][m * XSTR + t * 16 + n16] = 1.f / (1.f + __expf(-o));
        }
    }

    // ================= hop-0 (per wave, own elem) =============================
    const float e0 = __expf(ur_sh[wid][r1n]);
    float sum0 = e0;
    sum0 += __shfl_xor(sum0, 1);
    sum0 += __shfl_xor(sum0, 2);
    sum0 += __shfl_xor(sum0, 4);
    sum0 += __shfl_xor(sum0, 8);
    const float attn0 = e0 * __builtin_amdgcn_rcpf(sum0);

    float agg0 = 0.f, agg1 = 0.f;
    #pragma unroll
    for (int n = 0; n < NNB; ++n) {
        const float an = bcastf(attn0, n);
        agg0 = fmaf(an, sv_sh[wid][n * XSTR + d], agg0);
        agg1 = fmaf(an, gbuf[wid][n * XSTR + d], agg1);
    }

    // ---- iter0/hop0: sigmoid((sv0+agg0) @ W0 + b0)
    const float x0 = sv0 + agg0;
    float a0 = 0.f, a1 = 0.f, a2 = 0.f, a3 = 0.f;
    for (int k = 0; k < DIMN; k += 4) {
        const float* wr = W0 + k * DIMN;
        a0 = fmaf(bcastf(x0, k + 0), wr[d], a0);
        a1 = fmaf(bcastf(x0, k + 1), wr[DIMN + d], a1);
        a2 = fmaf(bcastf(x0, k + 2), wr[2 * DIMN + d], a2);
        a3 = fmaf(bcastf(x0, k + 3), wr[3 * DIMN + d], a3);
    }
    const float o0 = b0[d] + ((a0 + a1) + (a2 + a3));
    const float h0 = 1.f / (1.f + __expf(-o0));

    // ---- iter1/hop0: tanh((h0+agg1) @ W1 + b1)
    const float x1 = h0 + agg1;
    float c0 = 0.f, c1 = 0.f, c2 = 0.f, c3 = 0.f;
    for (int k = 0; k < DIMN; k += 4) {
        const float* wr = W1 + k * DIMN;
        c0 = fmaf(bcastf(x1, k + 0), wr[d], c0);
        c1 = fmaf(bcastf(x1, k + 1), wr[DIMN + d], c1);
        c2 = fmaf(bcastf(x1, k + 2), wr[2 * DIMN + d], c2);
        c3 = fmaf(bcastf(x1, k + 3), wr[3 * DIMN + d], c3);
    }
    const float o1 = b1[d] + ((c0 + c1) + (c2 + c3));
    const float item_d = 1.f - 2.f / (1.f + __expf(2.f * o1));  // tanh

    // ---- final: sigmoid(user . item)
    float p = user_d * item_d;
    p += __shfl_xor(p, 1);
    p += __shfl_xor(p, 2);
    p += __shfl_xor(p, 4);
    p += __shfl_xor(p, 8);
    p += __shfl_xor(p, 16);
    p += __shfl_xor(p, 32);
    if (d == 0) out[b] = 1.f / (1.f + __expf(-p));
}

extern "C" void kernel_launch(void* const* d_in, const int* in_sizes, int n_in,
                              void* d_out, int out_size, void* d_ws, size_t ws_size,
                              hipStream_t stream) {
    const int*   u       = (const int*)d_in[0];
    const int*   v       = (const int*)d_in[1];
    const int*   adj     = (const int*)d_in[2];
    const int*   rel_adj = (const int*)d_in[3];
    const float* usr_emb = (const float*)d_in[4];
    const float* ent_emb = (const float*)d_in[5];
    const float* rel_emb = (const float*)d_in[6];
    const float* W0      = (const float*)d_in[7];
    const float* b0      = (const float*)d_in[8];
    const float* W1      = (const float*)d_in[9];
    const float* b1      = (const float*)d_in[10];
    float* out = (float*)d_out;
    (void)d_ws; (void)ws_size;

    const int B = in_sizes[0];                 // 4096
    const int grid = (B + WPB - 1) / WPB;
    kgs_kernel<<<dim3(grid), dim3(64 * WPB), 0, stream>>>(
        u, v, adj, rel_adj, usr_emb, ent_emb, rel_emb, W0, b0, W1, b1,
        out, B);
}